// Round 6
// baseline (237.900 us; speedup 1.0000x reference)
//
#include <hip/hip_runtime.h>
#include <cstdint>
#include <cstddef>

typedef __bf16 bf16x8 __attribute__((ext_vector_type(8)));
typedef float f32x4 __attribute__((ext_vector_type(4)));
typedef unsigned int u32x2 __attribute__((ext_vector_type(2)));

#define MFMA16(a, b, c) __builtin_amdgcn_mfma_f32_16x16x32_bf16((a), (b), (c), 0, 0, 0)

// Barrier WITHOUT the vmcnt(0) drain __syncthreads() would emit: LDS ops must
// be visible (lgkmcnt(0)) but in-flight global prefetch loads stay in flight.
#define BAR() asm volatile("s_waitcnt lgkmcnt(0)\n\ts_barrier" ::: "memory")

static constexpr int CD = 128;
static constexpr int NTOK = 65536;
static constexpr float F_SCALE = 0.17677669529663688f;  // 1/sqrt(32)
static constexpr float F_LOG2E = 1.4426950408889634f;
static constexpr int PART = 4224;    // 4096 S + 128 Z floats per k1 block
static constexpr int NPARTS = 128;   // k1 blocks per batch

__device__ __forceinline__ unsigned pk2(float a, float b) {
  unsigned short ua = __builtin_bit_cast(unsigned short, (__bf16)a);
  unsigned short ub = __builtin_bit_cast(unsigned short, (__bf16)b);
  return (unsigned)ua | ((unsigned)ub << 16);
}

// One "group" = [16 c rows][64 n] fp32. Lane holds 4 CONSECUTIVE c rows
// (4r..4r+3) x 4 n ((lane&15)*4..+3). Each load instr: 16 lanes x 16B = 256B
// contiguous per row (full 128B lines), 4 rows per instr.
struct Grp { f32x4 M[4]; };

__device__ __forceinline__ Grp load_grp(const float* src, int lane) {
  Grp g;
  const float* p = src + (size_t)((lane >> 4) * 4) * NTOK + (lane & 15) * 4;
#pragma unroll
  for (int v = 0; v < 4; ++v) g.M[v] = *(const f32x4*)(p + (size_t)v * NTOK);
  return g;
}

// Pack lane's 4 consecutive c at each of 4 n into c-quad b64 writes to
// T2 [64 n][128 c] bf16, swizzle: phys_byte = logical ^ ((n&7)<<4).
// j-loop is DEPHASED per lane ((jj+nq)&3): within a 16-lane quarter-wave the
// 16 lanes hit 8 distinct granules instead of 2 -> 2-way (free) not 8-way.
__device__ __forceinline__ void pack_grp(const Grp& g, char* T2, int cqBase, int lane) {
  int cq = cqBase + (lane >> 4);
  int nq = lane & 15;
#pragma unroll
  for (int jj = 0; jj < 4; ++jj) {
    int j = (jj + nq) & 3;
    int n = nq * 4 + j;
    *(u32x2*)(T2 + n * 256 + ((cq * 8) ^ ((n & 7) << 4))) =
        u32x2{pk2(g.M[0][j], g.M[1][j]), pk2(g.M[2][j], g.M[3][j])};
  }
}

// ---------------- kernel 1: context -> S,Z partials ----------------
// grid 512 = 4 b x 128 chunks of 512 n, strips of 64 n. Wave w stages c-rows
// [w*32, w*32+32) x 64 n into shared T2 (dbuf, ONE cheap barrier/strip); wave
// w computes head w over all 64 n. E/V tiles + S-MFMA wave-private.
__global__ __launch_bounds__(256, 2) void k1_ctx(
    const float* __restrict__ ctx_in, const float* __restrict__ Wk,
    const float* __restrict__ Wv, float* __restrict__ S_part) {
  __shared__ char smem[64 * 1024];  // T2[2] 2x16KB | per-wave E 4K + V 4K
  const int tid = threadIdx.x;
  const int lane = tid & 63;
  const int w = tid >> 6;
  const int l15 = lane & 15;
  const int lg = lane >> 4;
  const int b = blockIdx.x >> 7;
  const int cb = blockIdx.x & 127;

  char* Eb = smem + 32 * 1024 + w * 8192;
  char* Vb = Eb + 4096;

  // Weight B-fragments for head w: col = weight row = w*32 + (m&1)*16 + l15,
  // k = c = ks*32 + lg*8 + e. m=0,1 -> Wk (prescaled by log2e); m=2,3 -> Wv.
  bf16x8 Wf[4][4];
#pragma unroll
  for (int m = 0; m < 4; ++m) {
    const float* Wp = (m < 2) ? Wk : Wv;
    const float sc = (m < 2) ? F_LOG2E : 1.0f;
    int row = w * 32 + (m & 1) * 16 + l15;
#pragma unroll
    for (int ks = 0; ks < 4; ++ks) {
      const float* p = Wp + row * CD + ks * 32 + lg * 8;
#pragma unroll
      for (int e = 0; e < 8; ++e) Wf[m][ks][e] = (__bf16)(p[e] * sc);
    }
  }

  f32x4 Sacc[2][2];
#pragma unroll
  for (int i = 0; i < 2; ++i)
#pragma unroll
    for (int j = 0; j < 2; ++j) Sacc[i][j] = f32x4{0.f, 0.f, 0.f, 0.f};
  float zacc[2] = {0.f, 0.f};

  // Wave w stages c-rows [w*32, +16) and [w*32+16, +16) (two groups).
  const float* srcA = ctx_in + (size_t)b * CD * NTOK + (size_t)(w * 32) * NTOK + cb * 512;
  const float* srcB = srcA + (size_t)16 * NTOK;

  Grp fa = load_grp(srcA, lane), fb = load_grp(srcB, lane);
#pragma unroll
  for (int s = 0; s < 8; ++s) {
    Grp na, nb;
    if (s < 7) {  // issue next strip's loads FIRST; they stay in flight across BAR
      na = load_grp(srcA + (s + 1) * 64, lane);
      nb = load_grp(srcB + (s + 1) * 64, lane);
    }
    char* T2 = smem + (s & 1) * 16384;
    pack_grp(fa, T2, w * 8, lane);
    pack_grp(fb, T2, w * 8 + 4, lane);
    BAR();  // T2[s&1] visible; prior compute's reads drained (lgkm only)

    // projections: D[n][wrow], n = t*16 + lg*4 + r, wrow col = l15
    f32x4 acc[4][4];
#pragma unroll
    for (int m = 0; m < 4; ++m)
#pragma unroll
      for (int t = 0; t < 4; ++t) acc[m][t] = f32x4{0.f, 0.f, 0.f, 0.f};
#pragma unroll
    for (int ks = 0; ks < 4; ++ks) {
      bf16x8 At[4];
#pragma unroll
      for (int t = 0; t < 4; ++t)
        At[t] = *(const bf16x8*)(T2 + (t * 16 + l15) * 256 +
                                 ((ks * 64 + lg * 16) ^ ((l15 & 7) << 4)));
#pragma unroll
      for (int m = 0; m < 4; ++m)
#pragma unroll
        for (int t = 0; t < 4; ++t) acc[m][t] = MFMA16(At[t], Wf[m][ks], acc[m][t]);
    }

    // exp + packed E/V into wave-private [32 d][64 n] bf16 tiles (2-way swz)
#pragma unroll
    for (int m = 0; m < 2; ++m) {
      int d = m * 16 + l15;
      int dx = (d & 7) << 4;
#pragma unroll
      for (int t = 0; t < 4; ++t) {
        f32x4 a = acc[m][t];
        float e0 = __builtin_exp2f(a[0]), e1 = __builtin_exp2f(a[1]);
        float e2 = __builtin_exp2f(a[2]), e3 = __builtin_exp2f(a[3]);
        zacc[m] += (e0 + e1) + (e2 + e3);
        *(u32x2*)(Eb + d * 128 + ((t * 32 + lg * 8) ^ dx)) =
            u32x2{pk2(e0, e1), pk2(e2, e3)};
        f32x4 v = acc[m + 2][t];
        *(u32x2*)(Vb + d * 128 + ((t * 32 + lg * 8) ^ dx)) =
            u32x2{pk2(v[0], v[1]), pk2(v[2], v[3])};
      }
    }

    // S[d][e] += E[d][n] * V[e][n], K = 64 (wave-private, no barrier)
#pragma unroll
    for (int s2 = 0; s2 < 2; ++s2) {
      bf16x8 Ea[2], Vv[2];
#pragma unroll
      for (int md = 0; md < 2; ++md) {
        int d = md * 16 + l15;
        int off = d * 128 + ((s2 * 64 + lg * 16) ^ ((d & 7) << 4));
        Ea[md] = *(const bf16x8*)(Eb + off);
        Vv[md] = *(const bf16x8*)(Vb + off);
      }
#pragma unroll
      for (int md = 0; md < 2; ++md)
#pragma unroll
        for (int ne = 0; ne < 2; ++ne) Sacc[md][ne] = MFMA16(Ea[md], Vv[ne], Sacc[md][ne]);
    }
    fa = na;
    fb = nb;
  }

  // Lane-linear partial writes (coalesced b128); mapping (used by k2b):
  // value (d = md*16+lg*4+r, e = ne*16+l15) at flat w*1024 + (md*2+ne)*256 + lane*4 + r
  float* outp = S_part + (size_t)blockIdx.x * PART;
#pragma unroll
  for (int md = 0; md < 2; ++md)
#pragma unroll
    for (int ne = 0; ne < 2; ++ne)
      *(f32x4*)(outp + w * 1024 + (md * 2 + ne) * 256 + lane * 4) = Sacc[md][ne];
#pragma unroll
  for (int m = 0; m < 2; ++m) {
    float z = zacc[m];
    z += __shfl_xor(z, 16, 64);
    z += __shfl_xor(z, 32, 64);
    if (lg == 0) outp[4096 + w * 32 + m * 16 + l15] = z;  // Z[h=w][d=m*16+l15]
  }
}

// ---------------- kernel 2a: reduce partials ----------------
__global__ void k2a_reduce(const float* __restrict__ S_part, float* __restrict__ S_red,
                           float* __restrict__ Z_red) {
  int bid = blockIdx.x;
  int b = bid / 33, bs = bid % 33;
  int tid = threadIdx.x;
  __shared__ float red[256];
  int e_loc = tid & 127, half = tid >> 7;
  const float* base =
      S_part + (size_t)b * NPARTS * PART + (bs < 32 ? bs * 128 + e_loc : 4096 + e_loc);
  float sum = 0.f;
  int h = NPARTS >> 1;
  for (int p = half * h; p < half * h + h; ++p) sum += base[(size_t)p * PART];
  red[tid] = sum;
  __syncthreads();
  if (tid < 128) {
    float v = red[tid] + red[tid + 128];
    if (bs < 32)
      S_red[b * 4096 + bs * 128 + tid] = v;
    else
      Z_red[b * 128 + tid] = v;
  }
}

// ---------------- kernel 2b: ctx = S/Z; T = Wo*ctx; W_eff = SCALE*T*Wq ----------------
__global__ void k2b_weff(const float* __restrict__ S_red, const float* __restrict__ Z_red,
                         const float* __restrict__ Wq, const float* __restrict__ Wo,
                         float* __restrict__ W_eff) {
  int b = blockIdx.x >> 3, og = blockIdx.x & 7;
  int tid = threadIdx.x;
  __shared__ float ctx_lds[4096];  // [h][d][e]
  __shared__ float T_lds[16 * 128];
  for (int i = tid * 16; i < tid * 16 + 16; ++i) {
    int h = i >> 10, d = (i >> 5) & 31, e = i & 31;
    int fl = h * 1024 + (((d >> 4) * 2 + (e >> 4)) << 8) + (((d >> 2) & 3) << 6) +
             ((e & 15) << 2) + (d & 3);
    ctx_lds[i] = S_red[b * 4096 + fl] / Z_red[b * 128 + h * 32 + d];
  }
  __syncthreads();
  {
    int o_loc = tid >> 4, hd0 = (tid & 15) * 8;
    int o = og * 16 + o_loc;
    for (int j = 0; j < 8; ++j) {
      int hd = hd0 + j, h = hd >> 5, d = hd & 31;
      const float* wo = Wo + o * 128 + h * 32;
      const float* cx = ctx_lds + h * 1024 + d * 32;
      float acc = 0.f;
      for (int e = 0; e < 32; ++e) acc += wo[e] * cx[e];
      T_lds[o_loc * 128 + hd] = acc;
    }
  }
  __syncthreads();
  {
    int o_loc = tid >> 4, c0 = (tid & 15) * 8;
    float acc[8] = {};
    const float* Trow = T_lds + o_loc * 128;
    for (int hd = 0; hd < 128; ++hd) {
      float tv = Trow[hd];
      const float* wq = Wq + hd * 128 + c0;
#pragma unroll
      for (int j = 0; j < 8; ++j) acc[j] += tv * wq[j];
    }
    float* op = W_eff + b * 16384 + (og * 16 + o_loc) * 128 + c0;
#pragma unroll
    for (int j = 0; j < 8; ++j) op[j] = F_SCALE * acc[j];
  }
}

// ---------------- kernel 3: out = W_eff[b] @ x[b] + bo ----------------
// grid 1024 = 4 b x 256 chunks of 256 n, 4 strips of 64 n. Block-cooperative:
// waves stage by c (256B/row loads) into shared T2 (dbuf, one cheap barrier
// per strip); wave w computes o in [w*32, +32) x 64 n; stores 4x16B
// back-to-back per row (256B contiguous) -> full-line writeback.
__global__ __launch_bounds__(256, 3) void k3_out(const float* __restrict__ x,
                                                 const float* __restrict__ W_eff,
                                                 const float* __restrict__ bo,
                                                 float* __restrict__ out) {
  __shared__ char smem[32 * 1024];  // T2 dbuf 2x16KB
  const int tid = threadIdx.x;
  const int lane = tid & 63;
  const int w = tid >> 6;
  const int l15 = lane & 15;
  const int lg = lane >> 4;
  const int b = blockIdx.x >> 8;
  const int cb = blockIdx.x & 255;

  bf16x8 Wf[2][4];
#pragma unroll
  for (int m = 0; m < 2; ++m) {
    int o = w * 32 + m * 16 + l15;
#pragma unroll
    for (int ks = 0; ks < 4; ++ks) {
      const float* p = W_eff + b * 16384 + o * 128 + ks * 32 + lg * 8;
#pragma unroll
      for (int e = 0; e < 8; ++e) Wf[m][ks][e] = (__bf16)p[e];
    }
  }
  float bof[2] = {bo[w * 32 + l15], bo[w * 32 + 16 + l15]};

  const float* srcA = x + (size_t)b * CD * NTOK + (size_t)(w * 32) * NTOK + cb * 256;
  const float* srcB = srcA + (size_t)16 * NTOK;
  float* dst = out + (size_t)b * CD * NTOK + cb * 256;

  Grp fa = load_grp(srcA, lane), fb = load_grp(srcB, lane);
#pragma unroll
  for (int s = 0; s < 4; ++s) {
    Grp na, nb;
    if (s < 3) {  // prefetch issue first; rides through BAR
      na = load_grp(srcA + (s + 1) * 64, lane);
      nb = load_grp(srcB + (s + 1) * 64, lane);
    }
    char* T2 = smem + (s & 1) * 16384;
    pack_grp(fa, T2, w * 8, lane);
    pack_grp(fb, T2, w * 8 + 4, lane);
    BAR();

    f32x4 acc[2][4];
#pragma unroll
    for (int m = 0; m < 2; ++m)
#pragma unroll
      for (int t = 0; t < 4; ++t) acc[m][t] = f32x4{0.f, 0.f, 0.f, 0.f};
#pragma unroll
    for (int ks = 0; ks < 4; ++ks) {
      bf16x8 At[4];
#pragma unroll
      for (int t = 0; t < 4; ++t)
        At[t] = *(const bf16x8*)(T2 + (t * 16 + l15) * 256 +
                                 ((ks * 64 + lg * 16) ^ ((l15 & 7) << 4)));
#pragma unroll
      for (int m = 0; m < 2; ++m)
#pragma unroll
        for (int t = 0; t < 4; ++t) acc[m][t] = MFMA16(At[t], Wf[m][ks], acc[m][t]);
    }

    // store: D[n][o] -> for fixed o row, 4 stores (t=0..3) cover 256B region
#pragma unroll
    for (int m = 0; m < 2; ++m) {
      int o = w * 32 + m * 16 + l15;
      float bb = bof[m];
      float* drow = dst + (size_t)o * NTOK + s * 64 + lg * 4;
#pragma unroll
      for (int t = 0; t < 4; ++t) {
        f32x4 v = acc[m][t];
        v[0] += bb; v[1] += bb; v[2] += bb; v[3] += bb;
        *(f32x4*)(drow + t * 16) = v;
      }
    }
    fa = na;
    fb = nb;
  }
}

extern "C" void kernel_launch(void* const* d_in, const int* in_sizes, int n_in,
                              void* d_out, int out_size, void* d_ws, size_t ws_size,
                              hipStream_t stream) {
  const float* x = (const float*)d_in[0];
  const float* ctxg = (const float*)d_in[1];
  const float* Wq = (const float*)d_in[2];
  const float* Wk = (const float*)d_in[3];
  const float* Wv = (const float*)d_in[4];
  const float* Wo = (const float*)d_in[5];
  const float* bo = (const float*)d_in[6];
  float* out = (float*)d_out;

  float* ws = (float*)d_ws;
  float* S_part = ws;                         // 512 * 4224 floats
  float* S_red = ws + (size_t)512 * PART;     // 16384
  float* Z_red = S_red + 16384;               // 512
  float* W_eff = Z_red + 512;                 // 65536

  k1_ctx<<<dim3(512), dim3(256), 0, stream>>>(ctxg, Wk, Wv, S_part);
  k2a_reduce<<<dim3(132), dim3(256), 0, stream>>>(S_part, S_red, Z_red);
  k2b_weff<<<dim3(32), dim3(256), 0, stream>>>(S_red, Z_red, Wq, Wo, W_eff);
  k3_out<<<dim3(1024), dim3(256), 0, stream>>>(x, W_eff, bo, out);
}

// Round 7
// 155.260 us; speedup vs baseline: 1.5323x; 1.5323x over previous
//
#include <hip/hip_runtime.h>
#include <cstdint>
#include <cstddef>

typedef __bf16 bf16x8 __attribute__((ext_vector_type(8)));
typedef float f32x4 __attribute__((ext_vector_type(4)));
typedef float f32x16 __attribute__((ext_vector_type(16)));
typedef unsigned int u32x2 __attribute__((ext_vector_type(2)));
typedef unsigned int u32x4 __attribute__((ext_vector_type(4)));

#define MFMA16(a, b, c) __builtin_amdgcn_mfma_f32_16x16x32_bf16((a), (b), (c), 0, 0, 0)
#define MFMA32(a, b, c) __builtin_amdgcn_mfma_f32_32x32x16_bf16((a), (b), (c), 0, 0, 0)

// Barrier WITHOUT the vmcnt(0) drain __syncthreads() emits: LDS visibility via
// lgkmcnt(0); in-flight global prefetch loads stay in flight across it.
#define BAR() asm volatile("s_waitcnt lgkmcnt(0)\n\ts_barrier" ::: "memory")

static constexpr int CD = 128;
static constexpr int NTOK = 65536;
static constexpr float F_SCALE = 0.17677669529663688f;  // 1/sqrt(32)
static constexpr float F_LOG2E = 1.4426950408889634f;
static constexpr int PART = 4224;    // 4096 S + 128 Z floats per k1 block
static constexpr int NPARTS = 128;   // k1 blocks per batch

__device__ __forceinline__ unsigned pk2(float a, float b) {
  unsigned short ua = __builtin_bit_cast(unsigned short, (__bf16)a);
  unsigned short ub = __builtin_bit_cast(unsigned short, (__bf16)b);
  return (unsigned)ua | ((unsigned)ub << 16);
}

__device__ __forceinline__ f32x16 z16() {
  f32x16 v;
#pragma unroll
  for (int i = 0; i < 16; ++i) v[i] = 0.f;
  return v;
}

// One "group" = [16 c rows][64 n] fp32. Lane holds 4 CONSECUTIVE c rows
// (4*(lane>>4)..+3) x 4 n ((lane&15)*4..+3). Per instr: 4 rows x 256B
// contiguous (full 128B lines). Compile-time indices only (rule #20).
struct Grp { f32x4 M[4]; };

__device__ __forceinline__ Grp load_grp(const float* src, int lane) {
  Grp g;
  const float* p = src + (size_t)((lane >> 4) * 4) * NTOK + (lane & 15) * 4;
#pragma unroll
  for (int v = 0; v < 4; ++v) g.M[v] = *(const f32x4*)(p + (size_t)v * NTOK);
  return g;
}

// T2 [64 n][128 c] bf16; swizzle: phys_byte = logical ^ ((n&15)<<4).
// Write: ~4-way; b128 reads: conflict-free (16 distinct granules / 16 lanes).
__device__ __forceinline__ void pack_grp(const Grp& g, char* T2, int cqBase, int lane) {
  int cq = cqBase + (lane >> 4);
  int nq = lane & 15;
#pragma unroll
  for (int j = 0; j < 4; ++j) {
    int n = nq * 4 + j;
    *(u32x2*)(T2 + n * 256 + ((cq * 8) ^ ((n & 15) << 4))) =
        u32x2{pk2(g.M[0][j], g.M[1][j]), pk2(g.M[2][j], g.M[3][j])};
  }
}

// ---------------- kernel 1: context -> S,Z partials ----------------
// grid 512 = 4 b x 128 chunks of 512 n (8 strips of 64). All 4 waves stage
// their 32 c-rows into shared T2 (dbuf, one lgkm-barrier/strip). Wave w =
// head w: 32x32x16 projection MFMAs (K'=Wk rows, V'=Wv rows), exp2 in regs,
// E/V -> S via v_permlane32_swap (NO E/V LDS), S-MFMA 32x32x16.
__global__ __launch_bounds__(256) __attribute__((amdgpu_waves_per_eu(2)))
void k1_ctx(const float* __restrict__ ctx_in, const float* __restrict__ Wk,
            const float* __restrict__ Wv, float* __restrict__ S_part) {
  __shared__ char smem[32 * 1024];  // T2 dbuf 2 x 16KB
  const int tid = threadIdx.x;
  const int lane = tid & 63;
  const int w = tid >> 6;
  const int l31 = lane & 31;
  const int l2 = lane >> 5;
  const int b = blockIdx.x >> 7;
  const int cb = blockIdx.x & 127;

  // B-fragments (32x32x16): col = weight row = w*32 + l31, k = c = ks*16 + l2*8 + e
  bf16x8 WfK[8], WfV[8];
#pragma unroll
  for (int ks = 0; ks < 8; ++ks) {
    const float* pK = Wk + (size_t)(w * 32 + l31) * CD + ks * 16 + l2 * 8;
    const float* pV = Wv + (size_t)(w * 32 + l31) * CD + ks * 16 + l2 * 8;
#pragma unroll
    for (int e = 0; e < 8; ++e) {
      WfK[ks][e] = (__bf16)(pK[e] * F_LOG2E);  // prescale: exp(x) = exp2(x*log2e)
      WfV[ks][e] = (__bf16)pV[e];
    }
  }

  f32x16 Sacc = z16();
  float zacc = 0.f;

  const float* srcA = ctx_in + (size_t)b * CD * NTOK + (size_t)(w * 32) * NTOK + cb * 512;
  const float* srcB = srcA + (size_t)16 * NTOK;

  Grp fa = load_grp(srcA, lane), fb = load_grp(srcB, lane);
#pragma unroll
  for (int s = 0; s < 8; ++s) {
    char* T2 = smem + (s & 1) * 16384;
    pack_grp(fa, T2, w * 8, lane);
    pack_grp(fb, T2, w * 8 + 4, lane);
    if (s < 7) {  // reload same regs; loads stay in flight across BAR + compute
      fa = load_grp(srcA + (s + 1) * 64, lane);
      fb = load_grp(srcB + (s + 1) * 64, lane);
    }
    BAR();

    // projection: D[n][wrow]: col = wrow = l31, row = n = (r&3)+8*(r>>2)+4*l2 + t*32
    unsigned pe[2][4][2], pv[2][4][2];
#pragma unroll
    for (int t = 0; t < 2; ++t) {
      f32x16 aK = z16(), aV = z16();
#pragma unroll
      for (int ks = 0; ks < 8; ++ks) {
        bf16x8 At = *(const bf16x8*)(T2 + (t * 32 + l31) * 256 +
                                     ((ks * 32 + l2 * 16) ^ ((l31 & 15) << 4)));
        aK = MFMA32(At, WfK[ks], aK);
        aV = MFMA32(At, WfV[ks], aV);
      }
#pragma unroll
      for (int q = 0; q < 4; ++q) {
        float e0 = __builtin_exp2f(aK[4 * q + 0]);
        float e1 = __builtin_exp2f(aK[4 * q + 1]);
        float e2 = __builtin_exp2f(aK[4 * q + 2]);
        float e3 = __builtin_exp2f(aK[4 * q + 3]);
        zacc += (e0 + e1) + (e2 + e3);
        pe[t][q][0] = pk2(e0, e1);
        pe[t][q][1] = pk2(e2, e3);
        pv[t][q][0] = pk2(aV[4 * q + 0], aV[4 * q + 1]);
        pv[t][q][1] = pk2(aV[4 * q + 2], aV[4 * q + 3]);
      }
    }

    // S[d][e] += E[d][n]V[e][n] over this strip's 64 n, as 4 K=16 windows.
    // Lane (l31,l2) holds X[col=l31][n = t*32 + 4*l2 + 8*q + s2] packed as
    // p[t][q][ps] (ps: s2-pairs). A/B frag for window nw (t=nw>>1, w2=nw&1)
    // needs n = 16*w2(+32t) + 8*l2 + e: first half from l2'=0 q=2w2+l2,
    // second from l2'=1 same q -> exactly one permlane32_swap per ps:
    //   swap(a=p[2w2][ps], b=p[2w2+1][ps]): a'=[a_lo|b_lo]=u32[ps],
    //   b'=[a_hi|b_hi]=u32[2+ps].
#pragma unroll
    for (int nw = 0; nw < 4; ++nw) {
      const int t = nw >> 1, w2 = nw & 1;
      unsigned ea0 = pe[t][2 * w2][0], eb0 = pe[t][2 * w2 + 1][0];
      unsigned ea1 = pe[t][2 * w2][1], eb1 = pe[t][2 * w2 + 1][1];
      asm("v_permlane32_swap_b32 %0, %1" : "+v"(ea0), "+v"(eb0));
      asm("v_permlane32_swap_b32 %0, %1" : "+v"(ea1), "+v"(eb1));
      unsigned va0 = pv[t][2 * w2][0], vb0 = pv[t][2 * w2 + 1][0];
      unsigned va1 = pv[t][2 * w2][1], vb1 = pv[t][2 * w2 + 1][1];
      asm("v_permlane32_swap_b32 %0, %1" : "+v"(va0), "+v"(vb0));
      asm("v_permlane32_swap_b32 %0, %1" : "+v"(va1), "+v"(vb1));
      bf16x8 Ea = __builtin_bit_cast(bf16x8, u32x4{ea0, ea1, eb0, eb1});
      bf16x8 Vb = __builtin_bit_cast(bf16x8, u32x4{va0, va1, vb0, vb1});
      Sacc = MFMA32(Ea, Vb, Sacc);
    }
  }

  // Partials: flat = w*1024 + lane*16 + r; (d,e) at lane=(e+32*((d>>2)&1)),
  // r = (d&3)+4*(d>>3)  [32x32 C/D layout]. Z at 4096 + w*32 + d.
  float* outp = S_part + (size_t)blockIdx.x * PART;
#pragma unroll
  for (int q = 0; q < 4; ++q) {
    f32x4 v{Sacc[4 * q + 0], Sacc[4 * q + 1], Sacc[4 * q + 2], Sacc[4 * q + 3]};
    *(f32x4*)(outp + w * 1024 + lane * 16 + q * 4) = v;
  }
  zacc += __shfl_xor(zacc, 32, 64);
  if (l2 == 0) outp[4096 + w * 32 + l31] = zacc;
}

// ---------------- kernel 2a: reduce partials ----------------
__global__ void k2a_reduce(const float* __restrict__ S_part, float* __restrict__ S_red,
                           float* __restrict__ Z_red) {
  int bid = blockIdx.x;
  int b = bid / 33, bs = bid % 33;
  int tid = threadIdx.x;
  __shared__ float red[256];
  int e_loc = tid & 127, half = tid >> 7;
  const float* base =
      S_part + (size_t)b * NPARTS * PART + (bs < 32 ? bs * 128 + e_loc : 4096 + e_loc);
  float sum = 0.f;
  int h = NPARTS >> 1;
  for (int p = half * h; p < half * h + h; ++p) sum += base[(size_t)p * PART];
  red[tid] = sum;
  __syncthreads();
  if (tid < 128) {
    float v = red[tid] + red[tid + 128];
    if (bs < 32)
      S_red[b * 4096 + bs * 128 + tid] = v;
    else
      Z_red[b * 128 + tid] = v;
  }
}

// ---------------- kernel 2b: ctx = S/Z; T = Wo*ctx; W_eff = SCALE*T*Wq ----------------
__global__ void k2b_weff(const float* __restrict__ S_red, const float* __restrict__ Z_red,
                         const float* __restrict__ Wq, const float* __restrict__ Wo,
                         float* __restrict__ W_eff) {
  int b = blockIdx.x >> 3, og = blockIdx.x & 7;
  int tid = threadIdx.x;
  __shared__ float ctx_lds[4096];  // [h][d][e]
  __shared__ float T_lds[16 * 128];
  for (int i = tid * 16; i < tid * 16 + 16; ++i) {
    int h = i >> 10, d = (i >> 5) & 31, e = i & 31;
    // inverse of k1's 32x32 partial layout
    int fl = h * 1024 + ((e + ((d >> 2) & 1) * 32) << 4) + (d & 3) + ((d >> 3) << 2);
    ctx_lds[i] = S_red[b * 4096 + fl] / Z_red[b * 128 + h * 32 + d];
  }
  __syncthreads();
  {
    int o_loc = tid >> 4, hd0 = (tid & 15) * 8;
    int o = og * 16 + o_loc;
    for (int j = 0; j < 8; ++j) {
      int hd = hd0 + j, h = hd >> 5, d = hd & 31;
      const float* wo = Wo + o * 128 + h * 32;
      const float* cx = ctx_lds + h * 1024 + d * 32;
      float acc = 0.f;
      for (int e = 0; e < 32; ++e) acc += wo[e] * cx[e];
      T_lds[o_loc * 128 + hd] = acc;
    }
  }
  __syncthreads();
  {
    int o_loc = tid >> 4, c0 = (tid & 15) * 8;
    float acc[8] = {};
    const float* Trow = T_lds + o_loc * 128;
    for (int hd = 0; hd < 128; ++hd) {
      float tv = Trow[hd];
      const float* wq = Wq + hd * 128 + c0;
#pragma unroll
      for (int j = 0; j < 8; ++j) acc[j] += tv * wq[j];
    }
    float* op = W_eff + b * 16384 + (og * 16 + o_loc) * 128 + c0;
#pragma unroll
    for (int j = 0; j < 8; ++j) op[j] = F_SCALE * acc[j];
  }
}

// ---------------- kernel 3: out = W_eff[b] @ x[b] + bo ----------------
// grid 1024 = 4 b x 256 chunks of 256 n (4 strips of 64). Shared T2 dbuf,
// lgkm-barrier; wave w -> o in [w*32,+32); 16x16x32 MFMA; per-t stores,
// 256B/row coverage per strip. Lean regs (~100) for 4 blocks/CU.
__global__ __launch_bounds__(256, 4) void k3_out(const float* __restrict__ x,
                                                 const float* __restrict__ W_eff,
                                                 const float* __restrict__ bo,
                                                 float* __restrict__ out) {
  __shared__ char smem[32 * 1024];  // T2 dbuf 2 x 16KB
  const int tid = threadIdx.x;
  const int lane = tid & 63;
  const int w = tid >> 6;
  const int l15 = lane & 15;
  const int lg = lane >> 4;
  const int b = blockIdx.x >> 8;
  const int cb = blockIdx.x & 255;

  bf16x8 Wf[2][4];
#pragma unroll
  for (int m = 0; m < 2; ++m) {
    int o = w * 32 + m * 16 + l15;
#pragma unroll
    for (int ks = 0; ks < 4; ++ks) {
      const float* p = W_eff + b * 16384 + o * 128 + ks * 32 + lg * 8;
#pragma unroll
      for (int e = 0; e < 8; ++e) Wf[m][ks][e] = (__bf16)p[e];
    }
  }
  float bof[2] = {bo[w * 32 + l15], bo[w * 32 + 16 + l15]};

  const float* srcA = x + (size_t)b * CD * NTOK + (size_t)(w * 32) * NTOK + cb * 256;
  const float* srcB = srcA + (size_t)16 * NTOK;
  float* dst = out + (size_t)b * CD * NTOK + cb * 256;

  Grp fa = load_grp(srcA, lane), fb = load_grp(srcB, lane);
#pragma unroll
  for (int s = 0; s < 4; ++s) {
    char* T2 = smem + (s & 1) * 16384;
    pack_grp(fa, T2, w * 8, lane);
    pack_grp(fb, T2, w * 8 + 4, lane);
    if (s < 3) {
      fa = load_grp(srcA + (s + 1) * 64, lane);
      fb = load_grp(srcB + (s + 1) * 64, lane);
    }
    BAR();

#pragma unroll
    for (int t = 0; t < 4; ++t) {
      f32x4 acc[2];
      acc[0] = f32x4{0.f, 0.f, 0.f, 0.f};
      acc[1] = f32x4{0.f, 0.f, 0.f, 0.f};
#pragma unroll
      for (int ks = 0; ks < 4; ++ks) {
        bf16x8 At = *(const bf16x8*)(T2 + (t * 16 + l15) * 256 +
                                     ((ks * 64 + lg * 16) ^ (l15 << 4)));
#pragma unroll
        for (int m = 0; m < 2; ++m) acc[m] = MFMA16(At, Wf[m][ks], acc[m]);
      }
#pragma unroll
      for (int m = 0; m < 2; ++m) {
        int o = w * 32 + m * 16 + l15;
        f32x4 v = acc[m];
        v[0] += bof[m]; v[1] += bof[m]; v[2] += bof[m]; v[3] += bof[m];
        *(f32x4*)(dst + (size_t)o * NTOK + s * 64 + t * 16 + lg * 4) = v;
      }
    }
  }
}

extern "C" void kernel_launch(void* const* d_in, const int* in_sizes, int n_in,
                              void* d_out, int out_size, void* d_ws, size_t ws_size,
                              hipStream_t stream) {
  const float* x = (const float*)d_in[0];
  const float* ctxg = (const float*)d_in[1];
  const float* Wq = (const float*)d_in[2];
  const float* Wk = (const float*)d_in[3];
  const float* Wv = (const float*)d_in[4];
  const float* Wo = (const float*)d_in[5];
  const float* bo = (const float*)d_in[6];
  float* out = (float*)d_out;

  float* ws = (float*)d_ws;
  float* S_part = ws;                         // 512 * 4224 floats
  float* S_red = ws + (size_t)512 * PART;     // 16384
  float* Z_red = S_red + 16384;               // 512
  float* W_eff = Z_red + 512;                 // 65536

  k1_ctx<<<dim3(512), dim3(256), 0, stream>>>(ctxg, Wk, Wv, S_part);
  k2a_reduce<<<dim3(132), dim3(256), 0, stream>>>(S_part, S_red, Z_red);
  k2b_weff<<<dim3(32), dim3(256), 0, stream>>>(S_red, Z_red, Wq, Wo, W_eff);
  k3_out<<<dim3(1024), dim3(256), 0, stream>>>(x, W_eff, bo, out);
}